// Round 20
// baseline (101.237 us; speedup 1.0000x reference)
//
#include <hip/hip_runtime.h>

#define Hc   192
#define Wc   192
#define HWc  (Hc * Wc)          // 36864
#define NPIX (4 * HWc)          // 147456
#define Hp   194                // padded rows: data at y+1 in [1,192]; rows 0,193 zero
#define Wp   256                // padded cols: data at x+2 in [2,193]; cols 0,1,194..255 zero
#define PLANE (Hp * Wp)         // px-slots per (b,dg) plane, 4 ch each
#define XTS  40                 // xt halo row stride in u16 (80 B)

typedef float f32x4 __attribute__((ext_vector_type(4)));
typedef float f32x2 __attribute__((ext_vector_type(2)));
typedef __bf16 bf16x8 __attribute__((ext_vector_type(8)));
typedef unsigned short u16;
typedef unsigned int u32;

// ---- workspace layout ----
#define WF_BO    0      // 224 (offset-conv bias, padded 216->224)
#define WF_B1    224
#define WF_B2A   256
#define WF_B2B   288
#define WF_BD    320    // end 352 floats = 1408 B
#define FR1_U    0      // conv1   [2][2][64][8]   2048
#define FRA_U    2048   // conv2a  [9][2][64][8]   9216
#define FRB_U    11264  // conv2b  [9][2][64][8]   9216
#define FRO_U    20480  // offset  [9][14][64][8]  64512
#define FRD_U    84992  // dcn     [9][2][64][8]   9216  (K-within-32 = dg*4+cg)
#define FRAG_U_TOT 94208
#define FRAG_BYTE 1408
#define T0_BYTE  (FRAG_BYTE + FRAG_U_TOT * 2)        // [NPIX][32] bf16 ch-last
#define T1_BYTE  (T0_BYTE + NPIX * 32 * 2)
#define IMG_BYTE (T1_BYTE + NPIX * 32 * 2)           // [4][8][Hp][Wp][4] bf16 zero-padded
#define IMG_SZ   ((size_t)4 * 8 * PLANE * 4 * 2)

__device__ __forceinline__ u16 f2bf(float f) {
    u32 u = __float_as_uint(f);
    u32 r = u + 0x7fffu + ((u >> 16) & 1u);
    return (u16)(r >> 16);
}
__device__ __forceinline__ float bf2f(u16 v) {
    return __uint_as_float(((u32)v) << 16);
}
__device__ __forceinline__ u32 cvtpk(float a, float b) {
    u32 r;
    asm("v_cvt_pk_bf16_f32 %0, %1, %2" : "=v"(r) : "v"(a), "v"(b));
    return r;
}
__device__ __forceinline__ f32x2 unpk(u32 h) {
    return f32x2{__uint_as_float(h << 16), __uint_as_float(h & 0xffff0000u)};
}

// ---------------- merged prologue: margin-zero of imgp (blocks 0..1599) + weight prep ----------------
__global__ __launch_bounds__(256) void zprep_k(
    u16* __restrict__ imgp,
    const float* __restrict__ w1,  const float* __restrict__ b1,
    const float* __restrict__ w2a, const float* __restrict__ b2a,
    const float* __restrict__ w2b, const float* __restrict__ b2b,
    const float* __restrict__ wo,  const float* __restrict__ bo,
    const float* __restrict__ wd,  const float* __restrict__ bd,
    float* __restrict__ wsf, u16* __restrict__ frag)
{
    const int bid = blockIdx.x;
    if (bid < 1600) {
        int i = bid * 256 + threadIdx.x;   // 0..409599
        int p = i / 12800;
        int r = i - p * 12800;
        int row, col;
        if (r < 512) {
            row = (r >> 8) * 193;       // 0 or 193
            col = r & 255;
        } else {
            int rr = r - 512;
            row = 1 + rr / 64;          // 1..192
            int cidx = rr & 63;
            col = (cidx < 2) ? cidx : (cidx + 192);   // {0,1} or {194..255}
        }
        *(uint2*)(imgp + ((size_t)p * PLANE + row * Wp + col) * 4) = uint2{0u, 0u};
        return;
    }

    int i = (bid - 1600) * 256 + threadIdx.x;
    if (i < 224)      { wsf[WF_BO + i]  = (i < 216) ? bo[i] : 0.f; return; }
    if (i < 256)      { wsf[WF_B1  + i - 224] = b1[i - 224];  return; }
    if (i < 288)      { wsf[WF_B2A + i - 256] = b2a[i - 256]; return; }
    if (i < 320)      { wsf[WF_B2B + i - 288] = b2b[i - 288]; return; }
    if (i < 352)      { wsf[WF_BD  + i - 320] = bd[i - 320];  return; }
    int fi = i - 352;
    if (fi < 2048) {          // conv1 frags
        int s = fi >> 10, l = (fi >> 3) & 63, j = fi & 7;
        int nt = (fi >> 9) & 1;
        int o = nt * 16 + (l & 15);
        int ci = s * 32 + ((l >> 4) << 3) + j;
        frag[FR1_U + fi] = f2bf(w1[o * 64 + ci]);
        return;
    }
    fi -= 2048;
    if (fi < 9216) {          // conv2a frags
        int s = fi / 1024, r = fi - s * 1024;
        int nt = r >> 9, l = (r >> 3) & 63, j = r & 7;
        int o = nt * 16 + (l & 15);
        int ci = ((l >> 4) << 3) + j;
        frag[FRA_U + fi] = f2bf(w2a[(o * 32 + ci) * 9 + s]);
        return;
    }
    fi -= 9216;
    if (fi < 9216) {          // conv2b frags
        int s = fi / 1024, r = fi - s * 1024;
        int nt = r >> 9, l = (r >> 3) & 63, j = r & 7;
        int o = nt * 16 + (l & 15);
        int ci = ((l >> 4) << 3) + j;
        frag[FRB_U + fi] = f2bf(w2b[(o * 32 + ci) * 9 + s]);
        return;
    }
    fi -= 9216;
    if (fi < 64512) {         // offset-conv frags, COUT padded to 224
        int s = fi / 7168, r = fi - s * 7168;
        int nt = r >> 9, l = (r >> 3) & 63, j = r & 7;
        int o = nt * 16 + (l & 15);
        int ci = ((l >> 4) << 3) + j;
        frag[FRO_U + fi] = f2bf((o < 216) ? wo[(o * 32 + ci) * 9 + s] : 0.f);
        return;
    }
    fi -= 64512;
    if (fi < 9216) {          // dcn frags
        int k = fi / 1024, r = fi - k * 1024;
        int nt = r >> 9, l = (r >> 3) & 63, j = r & 7;
        int o = nt * 16 + (l & 15);
        int ci = ((l >> 4) << 3) + j;
        frag[FRD_U + fi] = f2bf(wd[o * 288 + ci * 9 + k]);
        return;
    }
}

// ---------------- conv1x1 via MFMA ----------------
__global__ __launch_bounds__(256) void conv1x1_mfma_k(
    const float* __restrict__ f0, const float* __restrict__ f1,
    const u16* __restrict__ wfrag, const float* __restrict__ bias,
    u16* __restrict__ y, u16* __restrict__ dump)
{
    constexpr int M_BLK = 128;
    const int tid = threadIdx.x, lane = tid & 63, wv = tid >> 6;
    const int bid = blockIdx.x;
    const int swz = (bid & 7) * (gridDim.x >> 3) + (bid >> 3);
    const int m0 = swz * M_BLK;
    const int b = m0 / HWc, hwb = m0 - b * HWc;
    const int rm = wv * 32;

    __shared__ uint4 At4[512];

    int pxA[2], hA[2], wA[2], kgA[2];
#pragma unroll
    for (int it = 0; it < 2; ++it) {
        int st = it * 256 + tid;
        int rowl = ((st >> 6) << 4) | (st & 15);
        kgA[it] = (st >> 4) & 3;
        pxA[it] = rowl;
        int hwp = hwb + rowl;
        hA[it] = hwp / Wc;
        wA[it] = hwp - hA[it] * Wc;
    }

    f32x4 acc[2][2];
#pragma unroll
    for (int mf = 0; mf < 2; ++mf)
#pragma unroll
        for (int nf = 0; nf < 2; ++nf)
            acc[mf][nf] = f32x4{0.f, 0.f, 0.f, 0.f};

    for (int s = 0; s < 2; ++s) {
        const float* fs = (s == 0) ? f0 : f1;
#pragma unroll
        for (int it = 0; it < 2; ++it) {
            const float* pl = fs + ((size_t)b * 32 + kgA[it] * 8) * HWc + (hwb + pxA[it]);
            u32 p0, p1, p2, p3;
            {
                u32 a0 = f2bf(pl[0 * HWc]), a1 = f2bf(pl[1 * HWc]);
                u32 a2 = f2bf(pl[2 * HWc]), a3 = f2bf(pl[3 * HWc]);
                u32 a4 = f2bf(pl[4 * HWc]), a5 = f2bf(pl[5 * HWc]);
                u32 a6 = f2bf(pl[6 * HWc]), a7 = f2bf(pl[7 * HWc]);
                p0 = a0 | (a1 << 16); p1 = a2 | (a3 << 16);
                p2 = a4 | (a5 << 16); p3 = a6 | (a7 << 16);
            }
            uint4 v = {p0, p1, p2, p3};
            if (s == 1) {
                // zero-padded dg-planar dump: row = h+1, col = w+2
                size_t base = (((size_t)(b * 8 + kgA[it] * 2)) * PLANE
                               + (size_t)(hA[it] + 1) * Wp + (wA[it] + 2)) * 4;
                *(uint2*)(dump + base) = uint2{p0, p1};
                *(uint2*)(dump + base + (size_t)PLANE * 4) = uint2{p2, p3};
            }
            At4[it * 256 + tid] = v;
        }
        __syncthreads();

        bf16x8 aF[2];
#pragma unroll
        for (int mf = 0; mf < 2; ++mf)
            aF[mf] = __builtin_bit_cast(bf16x8, At4[((rm >> 4) + mf) * 64 + lane]);
#pragma unroll
        for (int nf = 0; nf < 2; ++nf) {
            bf16x8 bF = __builtin_bit_cast(
                bf16x8, *(const uint4*)(wfrag + (((size_t)s * 2 + nf) * 64 + lane) * 8));
#pragma unroll
            for (int mf = 0; mf < 2; ++mf)
                acc[mf][nf] = __builtin_amdgcn_mfma_f32_16x16x32_bf16(aF[mf], bF, acc[mf][nf], 0, 0, 0);
        }
        __syncthreads();
    }

#pragma unroll
    for (int nf = 0; nf < 2; ++nf) {
        int o = nf * 16 + (lane & 15);
        float bs = bias[o];
#pragma unroll
        for (int mf = 0; mf < 2; ++mf) {
#pragma unroll
            for (int r = 0; r < 4; ++r) {
                int m = m0 + rm + mf * 16 + ((lane >> 4) << 2) + r;
                y[(size_t)m * 32 + o] = f2bf(acc[mf][nf][r] + bs);
            }
        }
    }
}

// ---------------- 3x3 conv, halo-LDS single-barrier structure ----------------
__global__ __launch_bounds__(256, 4) void conv3x3h_k(
    const u16* __restrict__ src,   // [NPIX][32] bf16 ch-last
    const u16* __restrict__ wfrag, // [9][2][64][8]
    const float* __restrict__ bias,
    u16* __restrict__ dst)         // [NPIX][32]
{
    const int tid = threadIdx.x, lane = tid & 63, wv = tid >> 6;
    const int bid = blockIdx.x;
    const int swz = (bid & 7) * (gridDim.x >> 3) + (bid >> 3);
    const int m0 = swz * 64;
    const int b = m0 / HWc, hwb = m0 - b * HWc;
    const int h0 = hwb / Wc, w0 = hwb - h0 * Wc;

    __shared__ u16 xt[198 * XTS];   // 15840 B

#pragma unroll
    for (int it = 0; it < 4; ++it) {
        int t = it * 256 + tid;
        if (t < 792) {
            int s = t >> 2, c = t & 3;
            int ry = s / 66, cx = s - ry * 66;
            int row = h0 + ry - 1, col = w0 + cx - 1;
            uint4 v = {0u, 0u, 0u, 0u};
            if (((unsigned)row < (unsigned)Hc) && ((unsigned)col < (unsigned)Wc))
                v = *(const uint4*)(src + ((size_t)(b * HWc + row * Wc + col)) * 32 + c * 8);
            *(uint4*)(xt + (size_t)s * XTS + c * 8) = v;
        }
    }
    __syncthreads();

    f32x4 acc0 = {0.f, 0.f, 0.f, 0.f};
    f32x4 acc1 = {0.f, 0.f, 0.f, 0.f};
    const int r0 = wv * 16 + (lane & 15);
    const int kg8 = (lane >> 4) * 8;
#pragma unroll
    for (int kyi = 0; kyi < 3; ++kyi) {
#pragma unroll
        for (int kxi = 0; kxi < 3; ++kxi) {
            const int s9 = kyi * 3 + kxi;
            bf16x8 aF = __builtin_bit_cast(bf16x8,
                *(const uint4*)(xt + (size_t)(kyi * 66 + r0 + kxi) * XTS + kg8));
            bf16x8 bF0 = __builtin_bit_cast(bf16x8,
                *(const uint4*)(wfrag + (((size_t)s9 * 2 + 0) * 64 + lane) * 8));
            bf16x8 bF1 = __builtin_bit_cast(bf16x8,
                *(const uint4*)(wfrag + (((size_t)s9 * 2 + 1) * 64 + lane) * 8));
            acc0 = __builtin_amdgcn_mfma_f32_16x16x32_bf16(aF, bF0, acc0, 0, 0, 0);
            acc1 = __builtin_amdgcn_mfma_f32_16x16x32_bf16(aF, bF1, acc1, 0, 0, 0);
        }
    }

    const int oL = lane & 15;
    const float bs0 = bias[oL], bs1 = bias[16 + oL];
    u16* dp = dst + (size_t)(m0 + wv * 16 + ((lane >> 4) << 2)) * 32;
#pragma unroll
    for (int r = 0; r < 4; ++r) {
        dp[r * 32 + oL]      = f2bf(acc0[r] + bs0);
        dp[r * 32 + 16 + oL] = f2bf(acc1[r] + bs1);
    }
}

// ---------------- FUSED: offset conv + modulated deformable conv ----------------
__global__ __launch_bounds__(256, 4) void offdcn_k(
    const u16* __restrict__ t0,     // [NPIX][32] bf16 ch-last (feat)
    const u16* __restrict__ imgp,   // [4][8][Hp][Wp][4] bf16 zero-padded (col shift +2)
    const u16* __restrict__ wfragO, // [9][14][64][8]
    const u16* __restrict__ wfragD, // [9][2][64][8]
    const float* __restrict__ biasO,// 224
    const float* __restrict__ biasD,// 32
    float* __restrict__ out)        // [4][32][HW] f32
{
    const int tid = threadIdx.x, lane = tid & 63, wv = tid >> 6;
    const int bid = blockIdx.x;
    const int swz = (bid & 7) * (gridDim.x >> 3) + (bid >> 3);
    const int m0 = swz * 64;
    const int b = m0 / HWc, hwb = m0 - b * HWc;
    const int h0 = hwb / Wc, w0 = hwb - h0 * Wc;

    // union: xt[198][XTS] (15840 B) then co_s[224][66] (29568 B)
    __shared__ u16 pool[224 * 66];

    // ===== stage 0: halo -> xt (80B row stride) =====
    {
        u16* xt = pool;
#pragma unroll
        for (int it = 0; it < 4; ++it) {
            int t = it * 256 + tid;
            if (t < 792) {
                int s = t >> 2, c = t & 3;
                int ry = s / 66, cx = s - ry * 66;
                int row = h0 + ry - 1, col = w0 + cx - 1;
                uint4 v = {0u, 0u, 0u, 0u};
                if (((unsigned)row < (unsigned)Hc) && ((unsigned)col < (unsigned)Wc))
                    v = *(const uint4*)(t0 + ((size_t)(b * HWc + row * Wc + col)) * 32 + c * 8);
                *(uint4*)(xt + (size_t)s * XTS + c * 8) = v;
            }
        }
    }
    __syncthreads();

    // ===== phase 1: offset conv (no per-tap barriers, setprio'd MFMA cluster) =====
    const int wm = wv >> 1, wn = wv & 1;
    const int rm = wm * 32, cn = wn * 112;
    f32x4 acc[2][7];
#pragma unroll
    for (int mf = 0; mf < 2; ++mf)
#pragma unroll
        for (int nf = 0; nf < 7; ++nf)
            acc[mf][nf] = f32x4{0.f, 0.f, 0.f, 0.f};
    {
        const u16* xt = pool;
        const int r0 = rm + (lane & 15);
        const int kg8 = (lane >> 4) * 8;
        __builtin_amdgcn_s_setprio(1);
#pragma unroll
        for (int kyi = 0; kyi < 3; ++kyi) {
#pragma unroll
            for (int kxi = 0; kxi < 3; ++kxi) {
                const int s9 = kyi * 3 + kxi;
                bf16x8 aF0 = __builtin_bit_cast(bf16x8,
                    *(const uint4*)(xt + (size_t)(kyi * 66 + r0 + kxi) * XTS + kg8));
                bf16x8 aF1 = __builtin_bit_cast(bf16x8,
                    *(const uint4*)(xt + (size_t)(kyi * 66 + r0 + 16 + kxi) * XTS + kg8));
#pragma unroll
                for (int nf = 0; nf < 7; ++nf) {
                    bf16x8 bF = __builtin_bit_cast(
                        bf16x8,
                        *(const uint4*)(wfragO + (((size_t)s9 * 14 + wn * 7 + nf) * 64 + lane) * 8));
                    acc[0][nf] = __builtin_amdgcn_mfma_f32_16x16x32_bf16(aF0, bF, acc[0][nf], 0, 0, 0);
                    acc[1][nf] = __builtin_amdgcn_mfma_f32_16x16x32_bf16(aF1, bF, acc[1][nf], 0, 0, 0);
                }
            }
        }
        __builtin_amdgcn_s_setprio(0);
    }
    __syncthreads();   // all xt reads done before co_s overwrites the pool

    // ===== phase 1b: epilogue -> co_s =====
    u16* co_s = pool;
#pragma unroll
    for (int nf = 0; nf < 7; ++nf) {
        const int o = cn + nf * 16 + (lane & 15);
        const float bs = biasO[o];
        const bool sig = (o >= 144);
#pragma unroll
        for (int mf = 0; mf < 2; ++mf) {
            const int mb = rm + mf * 16 + ((lane >> 4) << 2);
            float v0 = acc[mf][nf][0] + bs, v1 = acc[mf][nf][1] + bs;
            float v2 = acc[mf][nf][2] + bs, v3 = acc[mf][nf][3] + bs;
            if (sig) {
                v0 = __builtin_amdgcn_rcpf(1.f + __builtin_amdgcn_exp2f(-v0 * 1.44269504f));
                v1 = __builtin_amdgcn_rcpf(1.f + __builtin_amdgcn_exp2f(-v1 * 1.44269504f));
                v2 = __builtin_amdgcn_rcpf(1.f + __builtin_amdgcn_exp2f(-v2 * 1.44269504f));
                v3 = __builtin_amdgcn_rcpf(1.f + __builtin_amdgcn_exp2f(-v3 * 1.44269504f));
            }
            *(u32*)&co_s[o * 66 + mb]     = cvtpk(v0, v1);
            *(u32*)&co_s[o * 66 + mb + 2] = cvtpk(v2, v3);
        }
    }
    __syncthreads();

    // ===== phase 2: DCN, fully-unrolled 3-tap batches, x-paired uint4 gathers =====
    {
        const int kg = lane >> 4;                 // dg pair {2kg, 2kg+1}
        const int pixb = wv * 16 + (lane & 15);   // pixel within block
        const int hw = hwb + pixb;
        const int hh = hw / Wc;
        const int wwp = hw - hh * Wc;
        const float fh = (float)(hh - 1);
        const float fw = (float)(wwp - 1);

        const u16* gb = imgp + (size_t)b * 8 * PLANE * 4;
        const u32 dgp[2] = {(u32)((2 * kg + 0) * (PLANE * 4)),
                            (u32)((2 * kg + 1) * (PLANE * 4))};

        f32x4 acc0 = {0.f, 0.f, 0.f, 0.f};
        f32x4 acc1 = {0.f, 0.f, 0.f, 0.f};

#pragma unroll
        for (int kb = 0; kb < 9; kb += 3) {
            float w4[3][2][4];            // w1x, wx, (1-wy)*m, wy*m
            uint4 cc[3][2][2];            // [t][dgi][row]: 2 x-corners x 4ch in one uint4

            // ---- stage A: co_s reads + addresses + issue ALL 12 paired gathers ----
#pragma unroll
            for (int t = 0; t < 3; ++t) {
                const int k = kb + t;
                const int kyi = k / 3, kxi = k - kyi * 3;
#pragma unroll
                for (int dgi = 0; dgi < 2; ++dgi) {
                    const int offch = (2 * kg + dgi) * 9 + k;
                    float dy = bf2f(co_s[offch * 66 + pixb]);
                    float dx = bf2f(co_s[(72 + offch) * 66 + pixb]);
                    float m  = bf2f(co_s[(144 + offch) * 66 + pixb]);

                    float py = dy + (fh + (float)kyi);
                    float px = dx + (fw + (float)kxi);
                    float y0f = floorf(py), x0f = floorf(px);
                    float wy = py - y0f, wx = px - x0f;
                    int y0 = (int)y0f, x0 = (int)x0f;

                    int yA = min(max(y0 + 1, 0), 193);
                    int yB = min(max(y0 + 2, 0), 193);
                    int xc = min(max(x0 + 2, 0), 254);  // uint4 covers cols xc, xc+1

                    float wym = wy * m;
                    w4[t][dgi][0] = 1.f - wx;
                    w4[t][dgi][1] = wx;
                    w4[t][dgi][2] = m - wym;            // (1-wy)*m
                    w4[t][dgi][3] = wym;

                    u32 rA = dgp[dgi] + ((u32)yA << 10);
                    u32 rB = dgp[dgi] + ((u32)yB << 10);
                    u32 xc4 = (u32)xc << 2;
                    cc[t][dgi][0] = *(const uint4*)(gb + (rA + xc4));
                    cc[t][dgi][1] = *(const uint4*)(gb + (rB + xc4));
                }
            }

            // ---- stage B: x-interp then y-interp (packed), cvt_pk, MFMA ----
#pragma unroll
            for (int t = 0; t < 3; ++t) {
                const int k = kb + t;
                u32 pk[4];
#pragma unroll
                for (int dgi = 0; dgi < 2; ++dgi) {
                    const float w1x = w4[t][dgi][0], wxs = w4[t][dgi][1];
                    const float w1ym = w4[t][dgi][2], wym = w4[t][dgi][3];
                    uint4 tp = cc[t][dgi][0], bt = cc[t][dgi][1];
                    f32x2 t01 = unpk(tp.x) * w1x + unpk(tp.z) * wxs;
                    f32x2 t23 = unpk(tp.y) * w1x + unpk(tp.w) * wxs;
                    f32x2 b01 = unpk(bt.x) * w1x + unpk(bt.z) * wxs;
                    f32x2 b23 = unpk(bt.y) * w1x + unpk(bt.w) * wxs;
                    f32x2 s01 = t01 * w1ym + b01 * wym;
                    f32x2 s23 = t23 * w1ym + b23 * wym;
                    pk[dgi * 2 + 0] = cvtpk(s01.x, s01.y);
                    pk[dgi * 2 + 1] = cvtpk(s23.x, s23.y);
                }

                bf16x8 aF = __builtin_bit_cast(bf16x8, uint4{pk[0], pk[1], pk[2], pk[3]});
                bf16x8 bF0 = __builtin_bit_cast(bf16x8,
                    *(const uint4*)(wfragD + ((size_t)(k * 2 + 0) * 64 + lane) * 8));
                bf16x8 bF1 = __builtin_bit_cast(bf16x8,
                    *(const uint4*)(wfragD + ((size_t)(k * 2 + 1) * 64 + lane) * 8));
                acc0 = __builtin_amdgcn_mfma_f32_16x16x32_bf16(aF, bF0, acc0, 0, 0, 0);
                acc1 = __builtin_amdgcn_mfma_f32_16x16x32_bf16(aF, bF1, acc1, 0, 0, 0);
            }
        }

        // epilogue: f32x4 stores (4 consecutive pixels per acc)
        const int hw0 = hwb + wv * 16 + ((lane >> 4) << 2);
        float* ob = out + (size_t)b * 32 * HWc;
        const int oL = lane & 15;
        const float bs0 = biasD[oL], bs1 = biasD[16 + oL];
        f32x4 o0 = {acc0[0] + bs0, acc0[1] + bs0, acc0[2] + bs0, acc0[3] + bs0};
        f32x4 o1 = {acc1[0] + bs1, acc1[1] + bs1, acc1[2] + bs1, acc1[3] + bs1};
        *(f32x4*)(ob + (size_t)oL * HWc + hw0) = o0;
        *(f32x4*)(ob + (size_t)(16 + oL) * HWc + hw0) = o1;
    }
}

extern "C" void kernel_launch(void* const* d_in, const int* in_sizes, int n_in,
                              void* d_out, int out_size, void* d_ws, size_t ws_size,
                              hipStream_t stream) {
    const float* img_ref  = (const float*)d_in[0];
    const float* img      = (const float*)d_in[1];
    const float* conv1_w  = (const float*)d_in[2];
    const float* conv1_b  = (const float*)d_in[3];
    const float* conv2a_w = (const float*)d_in[4];
    const float* conv2a_b = (const float*)d_in[5];
    const float* conv2b_w = (const float*)d_in[6];
    const float* conv2b_b = (const float*)d_in[7];
    const float* off_w    = (const float*)d_in[8];
    const float* off_b    = (const float*)d_in[9];
    const float* dcn_w    = (const float*)d_in[10];
    const float* dcn_b    = (const float*)d_in[11];

    float* wsf = (float*)d_ws;
    u16* frag = (u16*)((char*)d_ws + FRAG_BYTE);
    u16* t0   = (u16*)((char*)d_ws + T0_BYTE);
    u16* t1   = (u16*)((char*)d_ws + T1_BYTE);
    u16* imgp = (u16*)((char*)d_ws + IMG_BYTE);
    float* out = (float*)d_out;

    // merged prologue: margin-zero of imgp + weight prep (independent work)
    zprep_k<<<1970, 256, 0, stream>>>(imgp,
                                      conv1_w, conv1_b, conv2a_w, conv2a_b,
                                      conv2b_w, conv2b_b, off_w, off_b,
                                      dcn_w, dcn_b, wsf, frag);

    // conv1x1 -> t0 (ch-last) + padded dg-planar img dump
    conv1x1_mfma_k<<<NPIX / 128, 256, 0, stream>>>(
        img_ref, img, frag + FR1_U, wsf + WF_B1, t0, imgp);

    // conv2a: t0 -> t1 (halo single-barrier)
    conv3x3h_k<<<NPIX / 64, 256, 0, stream>>>(t0, frag + FRA_U, wsf + WF_B2A, t1);

    // conv2b: t1 -> t0
    conv3x3h_k<<<NPIX / 64, 256, 0, stream>>>(t1, frag + FRB_U, wsf + WF_B2B, t0);

    // fused offset conv + DCN
    offdcn_k<<<NPIX / 64, 256, 0, stream>>>(t0, imgp, frag + FRO_U, frag + FRD_U,
                                            wsf + WF_BO, wsf + WF_BD, out);
}

// Round 21
// 92.949 us; speedup vs baseline: 1.0892x; 1.0892x over previous
//
#include <hip/hip_runtime.h>

#define Hc   192
#define Wc   192
#define HWc  (Hc * Wc)          // 36864
#define NPIX (4 * HWc)          // 147456
#define Hp   194                // padded rows: data at y+1 in [1,192]; rows 0,193 zero
#define Wp   256                // padded cols: data at x+2 in [2,193]; cols 0,1,194..255 zero
#define PLANE (Hp * Wp)         // px-slots per (b,dg) plane, 4 ch each
#define XTS  40                 // xt halo row stride in u16 (80 B)

typedef float f32x4 __attribute__((ext_vector_type(4)));
typedef float f32x2 __attribute__((ext_vector_type(2)));
typedef __bf16 bf16x8 __attribute__((ext_vector_type(8)));
typedef unsigned short u16;
typedef unsigned int u32;

// ---- workspace layout ----
#define WF_BO    0      // 224 (offset-conv bias, padded 216->224)
#define WF_B1    224
#define WF_B2A   256
#define WF_B2B   288
#define WF_BD    320    // end 352 floats = 1408 B
#define FR1_U    0      // conv1   [2][2][64][8]   2048
#define FRA_U    2048   // conv2a  [9][2][64][8]   9216
#define FRB_U    11264  // conv2b  [9][2][64][8]   9216
#define FRO_U    20480  // offset  [9][14][64][8]  64512
#define FRD_U    84992  // dcn     [9][2][64][8]   9216  (K-within-32 = dg*4+cg)
#define FRAG_U_TOT 94208
#define FRAG_BYTE 1408
#define T0_BYTE  (FRAG_BYTE + FRAG_U_TOT * 2)        // [NPIX][32] bf16 ch-last
#define T1_BYTE  (T0_BYTE + NPIX * 32 * 2)
#define IMG_BYTE (T1_BYTE + NPIX * 32 * 2)           // [4][8][Hp][Wp][4] bf16 zero-padded
#define IMG_SZ   ((size_t)4 * 8 * PLANE * 4 * 2)

__device__ __forceinline__ u16 f2bf(float f) {
    u32 u = __float_as_uint(f);
    u32 r = u + 0x7fffu + ((u >> 16) & 1u);
    return (u16)(r >> 16);
}
__device__ __forceinline__ float bf2f(u16 v) {
    return __uint_as_float(((u32)v) << 16);
}
__device__ __forceinline__ u32 cvtpk(float a, float b) {
    u32 r;
    asm("v_cvt_pk_bf16_f32 %0, %1, %2" : "=v"(r) : "v"(a), "v"(b));
    return r;
}
__device__ __forceinline__ f32x2 unpk(u32 h) {
    return f32x2{__uint_as_float(h << 16), __uint_as_float(h & 0xffff0000u)};
}

// ---------------- merged prologue: margin-zero of imgp (blocks 0..1599) + weight prep ----------------
__global__ __launch_bounds__(256) void zprep_k(
    u16* __restrict__ imgp,
    const float* __restrict__ w1,  const float* __restrict__ b1,
    const float* __restrict__ w2a, const float* __restrict__ b2a,
    const float* __restrict__ w2b, const float* __restrict__ b2b,
    const float* __restrict__ wo,  const float* __restrict__ bo,
    const float* __restrict__ wd,  const float* __restrict__ bd,
    float* __restrict__ wsf, u16* __restrict__ frag)
{
    const int bid = blockIdx.x;
    if (bid < 1600) {
        int i = bid * 256 + threadIdx.x;   // 0..409599
        int p = i / 12800;
        int r = i - p * 12800;
        int row, col;
        if (r < 512) {
            row = (r >> 8) * 193;       // 0 or 193
            col = r & 255;
        } else {
            int rr = r - 512;
            row = 1 + rr / 64;          // 1..192
            int cidx = rr & 63;
            col = (cidx < 2) ? cidx : (cidx + 192);   // {0,1} or {194..255}
        }
        *(uint2*)(imgp + ((size_t)p * PLANE + row * Wp + col) * 4) = uint2{0u, 0u};
        return;
    }

    int i = (bid - 1600) * 256 + threadIdx.x;
    if (i < 224)      { wsf[WF_BO + i]  = (i < 216) ? bo[i] : 0.f; return; }
    if (i < 256)      { wsf[WF_B1  + i - 224] = b1[i - 224];  return; }
    if (i < 288)      { wsf[WF_B2A + i - 256] = b2a[i - 256]; return; }
    if (i < 320)      { wsf[WF_B2B + i - 288] = b2b[i - 288]; return; }
    if (i < 352)      { wsf[WF_BD  + i - 320] = bd[i - 320];  return; }
    int fi = i - 352;
    if (fi < 2048) {          // conv1 frags
        int s = fi >> 10, l = (fi >> 3) & 63, j = fi & 7;
        int nt = (fi >> 9) & 1;
        int o = nt * 16 + (l & 15);
        int ci = s * 32 + ((l >> 4) << 3) + j;
        frag[FR1_U + fi] = f2bf(w1[o * 64 + ci]);
        return;
    }
    fi -= 2048;
    if (fi < 9216) {          // conv2a frags
        int s = fi / 1024, r = fi - s * 1024;
        int nt = r >> 9, l = (r >> 3) & 63, j = r & 7;
        int o = nt * 16 + (l & 15);
        int ci = ((l >> 4) << 3) + j;
        frag[FRA_U + fi] = f2bf(w2a[(o * 32 + ci) * 9 + s]);
        return;
    }
    fi -= 9216;
    if (fi < 9216) {          // conv2b frags
        int s = fi / 1024, r = fi - s * 1024;
        int nt = r >> 9, l = (r >> 3) & 63, j = r & 7;
        int o = nt * 16 + (l & 15);
        int ci = ((l >> 4) << 3) + j;
        frag[FRB_U + fi] = f2bf(w2b[(o * 32 + ci) * 9 + s]);
        return;
    }
    fi -= 9216;
    if (fi < 64512) {         // offset-conv frags, COUT padded to 224
        int s = fi / 7168, r = fi - s * 7168;
        int nt = r >> 9, l = (r >> 3) & 63, j = r & 7;
        int o = nt * 16 + (l & 15);
        int ci = ((l >> 4) << 3) + j;
        frag[FRO_U + fi] = f2bf((o < 216) ? wo[(o * 32 + ci) * 9 + s] : 0.f);
        return;
    }
    fi -= 64512;
    if (fi < 9216) {          // dcn frags
        int k = fi / 1024, r = fi - k * 1024;
        int nt = r >> 9, l = (r >> 3) & 63, j = r & 7;
        int o = nt * 16 + (l & 15);
        int ci = ((l >> 4) << 3) + j;
        frag[FRD_U + fi] = f2bf(wd[o * 288 + ci * 9 + k]);
        return;
    }
}

// ---------------- conv1x1 via MFMA ----------------
__global__ __launch_bounds__(256) void conv1x1_mfma_k(
    const float* __restrict__ f0, const float* __restrict__ f1,
    const u16* __restrict__ wfrag, const float* __restrict__ bias,
    u16* __restrict__ y, u16* __restrict__ dump)
{
    constexpr int M_BLK = 128;
    const int tid = threadIdx.x, lane = tid & 63, wv = tid >> 6;
    const int bid = blockIdx.x;
    const int swz = (bid & 7) * (gridDim.x >> 3) + (bid >> 3);
    const int m0 = swz * M_BLK;
    const int b = m0 / HWc, hwb = m0 - b * HWc;
    const int rm = wv * 32;

    __shared__ uint4 At4[512];

    int pxA[2], hA[2], wA[2], kgA[2];
#pragma unroll
    for (int it = 0; it < 2; ++it) {
        int st = it * 256 + tid;
        int rowl = ((st >> 6) << 4) | (st & 15);
        kgA[it] = (st >> 4) & 3;
        pxA[it] = rowl;
        int hwp = hwb + rowl;
        hA[it] = hwp / Wc;
        wA[it] = hwp - hA[it] * Wc;
    }

    f32x4 acc[2][2];
#pragma unroll
    for (int mf = 0; mf < 2; ++mf)
#pragma unroll
        for (int nf = 0; nf < 2; ++nf)
            acc[mf][nf] = f32x4{0.f, 0.f, 0.f, 0.f};

    for (int s = 0; s < 2; ++s) {
        const float* fs = (s == 0) ? f0 : f1;
#pragma unroll
        for (int it = 0; it < 2; ++it) {
            const float* pl = fs + ((size_t)b * 32 + kgA[it] * 8) * HWc + (hwb + pxA[it]);
            u32 p0, p1, p2, p3;
            {
                u32 a0 = f2bf(pl[0 * HWc]), a1 = f2bf(pl[1 * HWc]);
                u32 a2 = f2bf(pl[2 * HWc]), a3 = f2bf(pl[3 * HWc]);
                u32 a4 = f2bf(pl[4 * HWc]), a5 = f2bf(pl[5 * HWc]);
                u32 a6 = f2bf(pl[6 * HWc]), a7 = f2bf(pl[7 * HWc]);
                p0 = a0 | (a1 << 16); p1 = a2 | (a3 << 16);
                p2 = a4 | (a5 << 16); p3 = a6 | (a7 << 16);
            }
            uint4 v = {p0, p1, p2, p3};
            if (s == 1) {
                // zero-padded dg-planar dump: row = h+1, col = w+2
                size_t base = (((size_t)(b * 8 + kgA[it] * 2)) * PLANE
                               + (size_t)(hA[it] + 1) * Wp + (wA[it] + 2)) * 4;
                *(uint2*)(dump + base) = uint2{p0, p1};
                *(uint2*)(dump + base + (size_t)PLANE * 4) = uint2{p2, p3};
            }
            At4[it * 256 + tid] = v;
        }
        __syncthreads();

        bf16x8 aF[2];
#pragma unroll
        for (int mf = 0; mf < 2; ++mf)
            aF[mf] = __builtin_bit_cast(bf16x8, At4[((rm >> 4) + mf) * 64 + lane]);
#pragma unroll
        for (int nf = 0; nf < 2; ++nf) {
            bf16x8 bF = __builtin_bit_cast(
                bf16x8, *(const uint4*)(wfrag + (((size_t)s * 2 + nf) * 64 + lane) * 8));
#pragma unroll
            for (int mf = 0; mf < 2; ++mf)
                acc[mf][nf] = __builtin_amdgcn_mfma_f32_16x16x32_bf16(aF[mf], bF, acc[mf][nf], 0, 0, 0);
        }
        __syncthreads();
    }

#pragma unroll
    for (int nf = 0; nf < 2; ++nf) {
        int o = nf * 16 + (lane & 15);
        float bs = bias[o];
#pragma unroll
        for (int mf = 0; mf < 2; ++mf) {
#pragma unroll
            for (int r = 0; r < 4; ++r) {
                int m = m0 + rm + mf * 16 + ((lane >> 4) << 2) + r;
                y[(size_t)m * 32 + o] = f2bf(acc[mf][nf][r] + bs);
            }
        }
    }
}

// ---------------- 3x3 conv, halo-LDS single-barrier structure ----------------
__global__ __launch_bounds__(256, 4) void conv3x3h_k(
    const u16* __restrict__ src,   // [NPIX][32] bf16 ch-last
    const u16* __restrict__ wfrag, // [9][2][64][8]
    const float* __restrict__ bias,
    u16* __restrict__ dst)         // [NPIX][32]
{
    const int tid = threadIdx.x, lane = tid & 63, wv = tid >> 6;
    const int bid = blockIdx.x;
    const int swz = (bid & 7) * (gridDim.x >> 3) + (bid >> 3);
    const int m0 = swz * 64;
    const int b = m0 / HWc, hwb = m0 - b * HWc;
    const int h0 = hwb / Wc, w0 = hwb - h0 * Wc;

    __shared__ u16 xt[198 * XTS];   // 15840 B, 80B row stride

#pragma unroll
    for (int it = 0; it < 4; ++it) {
        int t = it * 256 + tid;
        if (t < 792) {
            int s = t >> 2, c = t & 3;
            int ry = s / 66, cx = s - ry * 66;
            int row = h0 + ry - 1, col = w0 + cx - 1;
            uint4 v = {0u, 0u, 0u, 0u};
            if (((unsigned)row < (unsigned)Hc) && ((unsigned)col < (unsigned)Wc))
                v = *(const uint4*)(src + ((size_t)(b * HWc + row * Wc + col)) * 32 + c * 8);
            *(uint4*)(xt + (size_t)s * XTS + c * 8) = v;
        }
    }
    __syncthreads();

    f32x4 acc0 = {0.f, 0.f, 0.f, 0.f};
    f32x4 acc1 = {0.f, 0.f, 0.f, 0.f};
    const int r0 = wv * 16 + (lane & 15);
    const int kg8 = (lane >> 4) * 8;
#pragma unroll
    for (int kyi = 0; kyi < 3; ++kyi) {
#pragma unroll
        for (int kxi = 0; kxi < 3; ++kxi) {
            const int s9 = kyi * 3 + kxi;
            bf16x8 aF = __builtin_bit_cast(bf16x8,
                *(const uint4*)(xt + (size_t)(kyi * 66 + r0 + kxi) * XTS + kg8));
            bf16x8 bF0 = __builtin_bit_cast(bf16x8,
                *(const uint4*)(wfrag + (((size_t)s9 * 2 + 0) * 64 + lane) * 8));
            bf16x8 bF1 = __builtin_bit_cast(bf16x8,
                *(const uint4*)(wfrag + (((size_t)s9 * 2 + 1) * 64 + lane) * 8));
            acc0 = __builtin_amdgcn_mfma_f32_16x16x32_bf16(aF, bF0, acc0, 0, 0, 0);
            acc1 = __builtin_amdgcn_mfma_f32_16x16x32_bf16(aF, bF1, acc1, 0, 0, 0);
        }
    }

    const int oL = lane & 15;
    const float bs0 = bias[oL], bs1 = bias[16 + oL];
    u16* dp = dst + (size_t)(m0 + wv * 16 + ((lane >> 4) << 2)) * 32;
#pragma unroll
    for (int r = 0; r < 4; ++r) {
        dp[r * 32 + oL]      = f2bf(acc0[r] + bs0);
        dp[r * 32 + 16 + oL] = f2bf(acc1[r] + bs1);
    }
}

// ---------------- FUSED: offset conv + modulated deformable conv ----------------
__global__ __launch_bounds__(256, 4) void offdcn_k(
    const u16* __restrict__ t0,     // [NPIX][32] bf16 ch-last (feat)
    const u16* __restrict__ imgp,   // [4][8][Hp][Wp][4] bf16 zero-padded (col shift +2)
    const u16* __restrict__ wfragO, // [9][14][64][8]
    const u16* __restrict__ wfragD, // [9][2][64][8]
    const float* __restrict__ biasO,// 224
    const float* __restrict__ biasD,// 32
    float* __restrict__ out)        // [4][32][HW] f32
{
    const int tid = threadIdx.x, lane = tid & 63, wv = tid >> 6;
    const int bid = blockIdx.x;
    const int swz = (bid & 7) * (gridDim.x >> 3) + (bid >> 3);
    const int m0 = swz * 64;
    const int b = m0 / HWc, hwb = m0 - b * HWc;
    const int h0 = hwb / Wc, w0 = hwb - h0 * Wc;

    // union: xt[198][XTS] (15840 B) then co_s[224][66] (29568 B)
    __shared__ u16 pool[224 * 66];

    // ===== stage 0: halo -> xt (80B row stride) =====
    {
        u16* xt = pool;
#pragma unroll
        for (int it = 0; it < 4; ++it) {
            int t = it * 256 + tid;
            if (t < 792) {
                int s = t >> 2, c = t & 3;
                int ry = s / 66, cx = s - ry * 66;
                int row = h0 + ry - 1, col = w0 + cx - 1;
                uint4 v = {0u, 0u, 0u, 0u};
                if (((unsigned)row < (unsigned)Hc) && ((unsigned)col < (unsigned)Wc))
                    v = *(const uint4*)(t0 + ((size_t)(b * HWc + row * Wc + col)) * 32 + c * 8);
                *(uint4*)(xt + (size_t)s * XTS + c * 8) = v;
            }
        }
    }
    __syncthreads();

    // ===== phase 1: offset conv (no per-tap barriers) =====
    const int wm = wv >> 1, wn = wv & 1;
    const int rm = wm * 32, cn = wn * 112;
    f32x4 acc[2][7];
#pragma unroll
    for (int mf = 0; mf < 2; ++mf)
#pragma unroll
        for (int nf = 0; nf < 7; ++nf)
            acc[mf][nf] = f32x4{0.f, 0.f, 0.f, 0.f};
    {
        const u16* xt = pool;
        const int r0 = rm + (lane & 15);
        const int kg8 = (lane >> 4) * 8;
#pragma unroll
        for (int kyi = 0; kyi < 3; ++kyi) {
#pragma unroll
            for (int kxi = 0; kxi < 3; ++kxi) {
                const int s9 = kyi * 3 + kxi;
                bf16x8 aF0 = __builtin_bit_cast(bf16x8,
                    *(const uint4*)(xt + (size_t)(kyi * 66 + r0 + kxi) * XTS + kg8));
                bf16x8 aF1 = __builtin_bit_cast(bf16x8,
                    *(const uint4*)(xt + (size_t)(kyi * 66 + r0 + 16 + kxi) * XTS + kg8));
#pragma unroll
                for (int nf = 0; nf < 7; ++nf) {
                    bf16x8 bF = __builtin_bit_cast(
                        bf16x8,
                        *(const uint4*)(wfragO + (((size_t)s9 * 14 + wn * 7 + nf) * 64 + lane) * 8));
                    acc[0][nf] = __builtin_amdgcn_mfma_f32_16x16x32_bf16(aF0, bF, acc[0][nf], 0, 0, 0);
                    acc[1][nf] = __builtin_amdgcn_mfma_f32_16x16x32_bf16(aF1, bF, acc[1][nf], 0, 0, 0);
                }
            }
        }
    }
    __syncthreads();   // all xt reads done before co_s overwrites the pool

    // ===== phase 1b: epilogue -> co_s =====
    u16* co_s = pool;
#pragma unroll
    for (int nf = 0; nf < 7; ++nf) {
        const int o = cn + nf * 16 + (lane & 15);
        const float bs = biasO[o];
        const bool sig = (o >= 144);
#pragma unroll
        for (int mf = 0; mf < 2; ++mf) {
            const int mb = rm + mf * 16 + ((lane >> 4) << 2);
            float v0 = acc[mf][nf][0] + bs, v1 = acc[mf][nf][1] + bs;
            float v2 = acc[mf][nf][2] + bs, v3 = acc[mf][nf][3] + bs;
            if (sig) {
                v0 = __builtin_amdgcn_rcpf(1.f + __builtin_amdgcn_exp2f(-v0 * 1.44269504f));
                v1 = __builtin_amdgcn_rcpf(1.f + __builtin_amdgcn_exp2f(-v1 * 1.44269504f));
                v2 = __builtin_amdgcn_rcpf(1.f + __builtin_amdgcn_exp2f(-v2 * 1.44269504f));
                v3 = __builtin_amdgcn_rcpf(1.f + __builtin_amdgcn_exp2f(-v3 * 1.44269504f));
            }
            *(u32*)&co_s[o * 66 + mb]     = cvtpk(v0, v1);
            *(u32*)&co_s[o * 66 + mb + 2] = cvtpk(v2, v3);
        }
    }
    __syncthreads();

    // ===== phase 2: DCN, 3-tap batches, x-paired uint4 gathers =====
    {
        const int kg = lane >> 4;                 // dg pair {2kg, 2kg+1}
        const int pixb = wv * 16 + (lane & 15);   // pixel within block
        const int hw = hwb + pixb;
        const int hh = hw / Wc;
        const int wwp = hw - hh * Wc;
        const float fh = (float)(hh - 1);
        const float fw = (float)(wwp - 1);

        const u16* gb = imgp + (size_t)b * 8 * PLANE * 4;
        const u32 dgp[2] = {(u32)((2 * kg + 0) * (PLANE * 4)),
                            (u32)((2 * kg + 1) * (PLANE * 4))};

        f32x4 acc0 = {0.f, 0.f, 0.f, 0.f};
        f32x4 acc1 = {0.f, 0.f, 0.f, 0.f};

#pragma unroll 1
        for (int kb = 0; kb < 9; kb += 3) {
            float w4[3][2][4];            // w1x, wx, (1-wy)*m, wy*m
            uint4 cc[3][2][2];            // [t][dgi][row]: 2 x-corners x 4ch in one uint4

            // ---- stage A: co_s reads + addresses + issue ALL 12 paired gathers ----
#pragma unroll
            for (int t = 0; t < 3; ++t) {
                const int k = kb + t;
                const int kyi = k / 3, kxi = k - kyi * 3;
#pragma unroll
                for (int dgi = 0; dgi < 2; ++dgi) {
                    const int offch = (2 * kg + dgi) * 9 + k;
                    float dy = bf2f(co_s[offch * 66 + pixb]);
                    float dx = bf2f(co_s[(72 + offch) * 66 + pixb]);
                    float m  = bf2f(co_s[(144 + offch) * 66 + pixb]);

                    float py = dy + (fh + (float)kyi);
                    float px = dx + (fw + (float)kxi);
                    float y0f = floorf(py), x0f = floorf(px);
                    float wy = py - y0f, wx = px - x0f;
                    int y0 = (int)y0f, x0 = (int)x0f;

                    int yA = min(max(y0 + 1, 0), 193);
                    int yB = min(max(y0 + 2, 0), 193);
                    int xc = min(max(x0 + 2, 0), 254);  // uint4 covers cols xc, xc+1

                    float wym = wy * m;
                    w4[t][dgi][0] = 1.f - wx;
                    w4[t][dgi][1] = wx;
                    w4[t][dgi][2] = m - wym;            // (1-wy)*m
                    w4[t][dgi][3] = wym;

                    u32 rA = dgp[dgi] + ((u32)yA << 10);
                    u32 rB = dgp[dgi] + ((u32)yB << 10);
                    u32 xc4 = (u32)xc << 2;
                    cc[t][dgi][0] = *(const uint4*)(gb + (rA + xc4));
                    cc[t][dgi][1] = *(const uint4*)(gb + (rB + xc4));
                }
            }

            // ---- stage B: x-interp then y-interp (packed), cvt_pk, MFMA ----
#pragma unroll
            for (int t = 0; t < 3; ++t) {
                const int k = kb + t;
                u32 pk[4];
#pragma unroll
                for (int dgi = 0; dgi < 2; ++dgi) {
                    const float w1x = w4[t][dgi][0], wxs = w4[t][dgi][1];
                    const float w1ym = w4[t][dgi][2], wym = w4[t][dgi][3];
                    uint4 tp = cc[t][dgi][0], bt = cc[t][dgi][1];
                    f32x2 t01 = unpk(tp.x) * w1x + unpk(tp.z) * wxs;
                    f32x2 t23 = unpk(tp.y) * w1x + unpk(tp.w) * wxs;
                    f32x2 b01 = unpk(bt.x) * w1x + unpk(bt.z) * wxs;
                    f32x2 b23 = unpk(bt.y) * w1x + unpk(bt.w) * wxs;
                    f32x2 s01 = t01 * w1ym + b01 * wym;
                    f32x2 s23 = t23 * w1ym + b23 * wym;
                    pk[dgi * 2 + 0] = cvtpk(s01.x, s01.y);
                    pk[dgi * 2 + 1] = cvtpk(s23.x, s23.y);
                }

                bf16x8 aF = __builtin_bit_cast(bf16x8, uint4{pk[0], pk[1], pk[2], pk[3]});
                bf16x8 bF0 = __builtin_bit_cast(bf16x8,
                    *(const uint4*)(wfragD + ((size_t)(k * 2 + 0) * 64 + lane) * 8));
                bf16x8 bF1 = __builtin_bit_cast(bf16x8,
                    *(const uint4*)(wfragD + ((size_t)(k * 2 + 1) * 64 + lane) * 8));
                acc0 = __builtin_amdgcn_mfma_f32_16x16x32_bf16(aF, bF0, acc0, 0, 0, 0);
                acc1 = __builtin_amdgcn_mfma_f32_16x16x32_bf16(aF, bF1, acc1, 0, 0, 0);
            }
        }

        // epilogue: f32x4 stores (4 consecutive pixels per acc)
        const int hw0 = hwb + wv * 16 + ((lane >> 4) << 2);
        float* ob = out + (size_t)b * 32 * HWc;
        const int oL = lane & 15;
        const float bs0 = biasD[oL], bs1 = biasD[16 + oL];
        f32x4 o0 = {acc0[0] + bs0, acc0[1] + bs0, acc0[2] + bs0, acc0[3] + bs0};
        f32x4 o1 = {acc1[0] + bs1, acc1[1] + bs1, acc1[2] + bs1, acc1[3] + bs1};
        *(f32x4*)(ob + (size_t)oL * HWc + hw0) = o0;
        *(f32x4*)(ob + (size_t)(16 + oL) * HWc + hw0) = o1;
    }
}

extern "C" void kernel_launch(void* const* d_in, const int* in_sizes, int n_in,
                              void* d_out, int out_size, void* d_ws, size_t ws_size,
                              hipStream_t stream) {
    const float* img_ref  = (const float*)d_in[0];
    const float* img      = (const float*)d_in[1];
    const float* conv1_w  = (const float*)d_in[2];
    const float* conv1_b  = (const float*)d_in[3];
    const float* conv2a_w = (const float*)d_in[4];
    const float* conv2a_b = (const float*)d_in[5];
    const float* conv2b_w = (const float*)d_in[6];
    const float* conv2b_b = (const float*)d_in[7];
    const float* off_w    = (const float*)d_in[8];
    const float* off_b    = (const float*)d_in[9];
    const float* dcn_w    = (const float*)d_in[10];
    const float* dcn_b    = (const float*)d_in[11];

    float* wsf = (float*)d_ws;
    u16* frag = (u16*)((char*)d_ws + FRAG_BYTE);
    u16* t0   = (u16*)((char*)d_ws + T0_BYTE);
    u16* t1   = (u16*)((char*)d_ws + T1_BYTE);
    u16* imgp = (u16*)((char*)d_ws + IMG_BYTE);
    float* out = (float*)d_out;

    // merged prologue: margin-zero of imgp + weight prep (independent work)
    zprep_k<<<1970, 256, 0, stream>>>(imgp,
                                      conv1_w, conv1_b, conv2a_w, conv2a_b,
                                      conv2b_w, conv2b_b, off_w, off_b,
                                      dcn_w, dcn_b, wsf, frag);

    // conv1x1 -> t0 (ch-last) + padded dg-planar img dump
    conv1x1_mfma_k<<<NPIX / 128, 256, 0, stream>>>(
        img_ref, img, frag + FR1_U, wsf + WF_B1, t0, imgp);

    // conv2a: t0 -> t1 (halo single-barrier)
    conv3x3h_k<<<NPIX / 64, 256, 0, stream>>>(t0, frag + FRA_U, wsf + WF_B2A, t1);

    // conv2b: t1 -> t0
    conv3x3h_k<<<NPIX / 64, 256, 0, stream>>>(t1, frag + FRB_U, wsf + WF_B2B, t0);

    // fused offset conv + DCN
    offdcn_k<<<NPIX / 64, 256, 0, stream>>>(t0, imgp, frag + FRO_U, frag + FRD_U,
                                            wsf + WF_BO, wsf + WF_BD, out);
}